// Round 4
// baseline (783.487 us; speedup 1.0000x reference)
//
#include <hip/hip_runtime.h>

#define NND 50000
#define NED 800000
#define NF  128
#define NH  64

// ---- workspace byte offsets (all 16B aligned) ----
#define WS_HA     0                         // float[NND*64]      12,800,000 B
#define WS_STATS  12800000                  // double[4][128]      4,096 B (sum, sumsq per stage)
#define WS_SS     (WS_STATS + 4*128*8)      // float[4][128]       2,048 B (scale, shift per stage)
#define WS_DEG    (WS_SS + 4*128*4)         // int[NND]
#define WS_OFFS   (WS_DEG + NND*4)          // int[NND+4]
#define WS_CUR    (WS_OFFS + (NND+4)*4)     // int[NND]
#define WS_ESRC   (WS_CUR + NND*4)          // int[NED]

// ---------------- CSR build ----------------
__global__ void k_deg(const int* __restrict__ dst, int* __restrict__ deg) {
    int e = blockIdx.x * 256 + threadIdx.x;
    if (e < NED) atomicAdd(&deg[dst[e]], 1);
}

__global__ __launch_bounds__(1024) void k_scan(const int* __restrict__ deg,
                                               int* __restrict__ offs) {
    __shared__ int sd[1024];
    int t = threadIdx.x;
    const int C = (NND + 1023) / 1024;   // 49
    int s = t * C; if (s > NND) s = NND;
    int e = s + C; if (e > NND) e = NND;
    int loc = 0;
    for (int i = s; i < e; ++i) loc += deg[i];
    sd[t] = loc;
    __syncthreads();
    for (int off = 1; off < 1024; off <<= 1) {
        int v = (t >= off) ? sd[t - off] : 0;
        __syncthreads();
        sd[t] += v;
        __syncthreads();
    }
    int run = sd[t] - loc;   // exclusive prefix
    for (int i = s; i < e; ++i) { offs[i] = run; run += deg[i]; }
    if (t == 1023) offs[NND] = sd[1023];
}

__global__ void k_fill(const int* __restrict__ src, const int* __restrict__ dst,
                       int* __restrict__ cur, int* __restrict__ esrc) {
    int e = blockIdx.x * 256 + threadIdx.x;
    if (e < NED) {
        int d = dst[e];
        int pos = atomicAdd(&cur[d], 1);
        esrc[pos] = src[e];
    }
}

// ---------------- input transform: h0 = x @ W_t + b_t (raw) + stats ----------------
__global__ __launch_bounds__(256) void k_transform(const float* __restrict__ x,
                                                   const float* __restrict__ Wt,
                                                   const float* __restrict__ bt,
                                                   float* __restrict__ outraw,
                                                   double* __restrict__ stats) {
    __shared__ float Wl[NF * NH];   // 32 KB
    __shared__ float sT[64 * 68];   // 17 KB, transposed x half-tile (pad 68 keeps b128 aligned)
    int tid = threadIdx.x;

#pragma unroll
    for (int r = 0; r < 8; ++r) {
        int i4 = r * 256 + tid;
        ((float4*)Wl)[i4] = ((const float4*)Wt)[i4];
    }

    int c = tid & 63, w = tid >> 6;       // phase-1 layout: lane=feature, wave=node
    int tn = tid & 15, tc = tid >> 4;     // GEMM layout: 4 nodes x 4 cols per thread
    int base = blockIdx.x * 64;

    float acc[4][4];
#pragma unroll
    for (int i = 0; i < 4; ++i)
#pragma unroll
        for (int j = 0; j < 4; ++j) acc[i][j] = 0.f;

    for (int half = 0; half < 2; ++half) {
        __syncthreads();
        // stage xT[k][node] for k in [half*64, half*64+64)
#pragma unroll
        for (int s = 0; s < 16; ++s) {
            int nl = s * 4 + w;
            int n = base + nl;
            float v = 0.f;
            if (n < NND) v = x[(size_t)n * NF + half * 64 + c];
            sT[c * 68 + nl] = v;
        }
        __syncthreads();
#pragma unroll 8
        for (int k = 0; k < 64; ++k) {
            float4 a  = *(const float4*)&sT[k * 68 + tn * 4];
            float4 wv = *(const float4*)&Wl[(half * 64 + k) * NH + tc * 4];
            float av[4]  = {a.x, a.y, a.z, a.w};
            float wvv[4] = {wv.x, wv.y, wv.z, wv.w};
#pragma unroll
            for (int i = 0; i < 4; ++i)
#pragma unroll
                for (int j = 0; j < 4; ++j) acc[i][j] += av[i] * wvv[j];
        }
    }

    float4 bv = ((const float4*)bt)[tc];
    float bj[4] = {bv.x, bv.y, bv.z, bv.w};

    double sum[4] = {0, 0, 0, 0}, ssq[4] = {0, 0, 0, 0};
#pragma unroll
    for (int i = 0; i < 4; ++i) {
        int n = base + tn * 4 + i;
        if (n < NND) {
            float o0 = acc[i][0] + bj[0], o1 = acc[i][1] + bj[1];
            float o2 = acc[i][2] + bj[2], o3 = acc[i][3] + bj[3];
            float4 o = {o0, o1, o2, o3};
            *(float4*)&outraw[(size_t)n * NH + tc * 4] = o;
            sum[0] += o0; ssq[0] += (double)o0 * o0;
            sum[1] += o1; ssq[1] += (double)o1 * o1;
            sum[2] += o2; ssq[2] += (double)o2 * o2;
            sum[3] += o3; ssq[3] += (double)o3 * o3;
        }
    }
#pragma unroll
    for (int m = 1; m < 16; m <<= 1) {
#pragma unroll
        for (int j = 0; j < 4; ++j) {
            sum[j] += __shfl_xor(sum[j], m);
            ssq[j] += __shfl_xor(ssq[j], m);
        }
    }
    if (tn == 0) {
#pragma unroll
        for (int j = 0; j < 4; ++j) {
            atomicAdd(&stats[tc * 4 + j], sum[j]);
            atomicAdd(&stats[64 + tc * 4 + j], ssq[j]);
        }
    }
}

// ---------------- BN finalize: scale/shift from accumulated stats ----------------
__global__ void k_finalize(const double* __restrict__ st,
                           const float* __restrict__ g, const float* __restrict__ b,
                           float* __restrict__ ssout) {
    int c = threadIdx.x;   // 64 threads
    double mu  = st[c] / (double)NND;
    double var = st[64 + c] / (double)NND - mu * mu;
    if (var < 0.0) var = 0.0;
    double rs = 1.0 / sqrt(var + 1e-5);
    double sc = (double)g[c] * rs;
    ssout[c]      = (float)sc;
    ssout[64 + c] = (float)((double)b[c] - mu * sc);
}

// ---------------- fused GIN layer: BN-apply + aggregate + MLP + relu + stats ----------------
__global__ __launch_bounds__(256) void k_layer(const float* __restrict__ inraw,
                                               float* __restrict__ outraw,
                                               const float* __restrict__ ssin,
                                               double* __restrict__ statsout,
                                               const float* __restrict__ W1,
                                               const float* __restrict__ W2,
                                               const int* __restrict__ offs,
                                               const int* __restrict__ esrc) {
    __shared__ float W1l[NH * NH];   // 16 KB
    __shared__ float W2l[NH * NH];   // 16 KB
    __shared__ float sT[64 * 68];    // 17 KB, shared by aggT then t1T
    int tid = threadIdx.x;

#pragma unroll
    for (int r = 0; r < 4; ++r) {
        int i4 = r * 256 + tid;
        ((float4*)W1l)[i4] = ((const float4*)W1)[i4];
        ((float4*)W2l)[i4] = ((const float4*)W2)[i4];
    }

    int c = tid & 63, w = tid >> 6;
    float sc = ssin[c], sh = ssin[64 + c];
    int base = blockIdx.x * 64;

    // phase 1: aggregate raw rows (self + neighbors), fold BN, write transposed to LDS
#pragma unroll 1
    for (int s = 0; s < 16; ++s) {
        int nl = s * 4 + w;
        int n = base + nl;
        float aggv = 0.f;
        if (n < NND) {
            float sum = inraw[(size_t)n * NH + c];
            int e0 = offs[n], e1 = offs[n + 1];
            int deg = e1 - e0;
            int e = e0;
            for (; e + 4 <= e1; e += 4) {
                int j0 = esrc[e], j1 = esrc[e + 1], j2 = esrc[e + 2], j3 = esrc[e + 3];
                float v0 = inraw[(size_t)j0 * NH + c];
                float v1 = inraw[(size_t)j1 * NH + c];
                float v2 = inraw[(size_t)j2 * NH + c];
                float v3 = inraw[(size_t)j3 * NH + c];
                sum += v0 + v1 + v2 + v3;
            }
            for (; e < e1; ++e) sum += inraw[(size_t)esrc[e] * NH + c];
            aggv = sc * sum + (float)(deg + 1) * sh;
        }
        sT[c * 68 + nl] = aggv;
    }
    __syncthreads();

    int tn = tid & 15, tc = tid >> 4;

    // GEMM1: t1 = relu(agg @ W1)
    float a1[4][4];
#pragma unroll
    for (int i = 0; i < 4; ++i)
#pragma unroll
        for (int j = 0; j < 4; ++j) a1[i][j] = 0.f;
#pragma unroll 8
    for (int k = 0; k < 64; ++k) {
        float4 a  = *(const float4*)&sT[k * 68 + tn * 4];
        float4 wv = *(const float4*)&W1l[k * NH + tc * 4];
        float av[4]  = {a.x, a.y, a.z, a.w};
        float wvv[4] = {wv.x, wv.y, wv.z, wv.w};
#pragma unroll
        for (int i = 0; i < 4; ++i)
#pragma unroll
            for (int j = 0; j < 4; ++j) a1[i][j] += av[i] * wvv[j];
    }
#pragma unroll
    for (int i = 0; i < 4; ++i)
#pragma unroll
        for (int j = 0; j < 4; ++j) a1[i][j] = fmaxf(a1[i][j], 0.f);

    __syncthreads();   // all aggT reads done before overwriting sT with t1T
#pragma unroll
    for (int j = 0; j < 4; ++j) {
        float4 t = {a1[0][j], a1[1][j], a1[2][j], a1[3][j]};
        *(float4*)&sT[(tc * 4 + j) * 68 + tn * 4] = t;
    }
    __syncthreads();

    // GEMM2: t2 = relu(t1 @ W2)
    float a2[4][4];
#pragma unroll
    for (int i = 0; i < 4; ++i)
#pragma unroll
        for (int j = 0; j < 4; ++j) a2[i][j] = 0.f;
#pragma unroll 8
    for (int k = 0; k < 64; ++k) {
        float4 a  = *(const float4*)&sT[k * 68 + tn * 4];
        float4 wv = *(const float4*)&W2l[k * NH + tc * 4];
        float av[4]  = {a.x, a.y, a.z, a.w};
        float wvv[4] = {wv.x, wv.y, wv.z, wv.w};
#pragma unroll
        for (int i = 0; i < 4; ++i)
#pragma unroll
            for (int j = 0; j < 4; ++j) a2[i][j] += av[i] * wvv[j];
    }

    double sum[4] = {0, 0, 0, 0}, ssq[4] = {0, 0, 0, 0};
#pragma unroll
    for (int i = 0; i < 4; ++i) {
        int n = base + tn * 4 + i;
        if (n < NND) {
            float o0 = fmaxf(a2[i][0], 0.f), o1 = fmaxf(a2[i][1], 0.f);
            float o2 = fmaxf(a2[i][2], 0.f), o3 = fmaxf(a2[i][3], 0.f);
            float4 o = {o0, o1, o2, o3};
            *(float4*)&outraw[(size_t)n * NH + tc * 4] = o;
            sum[0] += o0; ssq[0] += (double)o0 * o0;
            sum[1] += o1; ssq[1] += (double)o1 * o1;
            sum[2] += o2; ssq[2] += (double)o2 * o2;
            sum[3] += o3; ssq[3] += (double)o3 * o3;
        }
    }
#pragma unroll
    for (int m = 1; m < 16; m <<= 1) {
#pragma unroll
        for (int j = 0; j < 4; ++j) {
            sum[j] += __shfl_xor(sum[j], m);
            ssq[j] += __shfl_xor(ssq[j], m);
        }
    }
    if (tn == 0) {
#pragma unroll
        for (int j = 0; j < 4; ++j) {
            atomicAdd(&statsout[tc * 4 + j], sum[j]);
            atomicAdd(&statsout[64 + tc * 4 + j], ssq[j]);
        }
    }
}

// ---------------- final BN apply, in-place on d_out ----------------
__global__ void k_bnout(float* __restrict__ h, const float* __restrict__ ss) {
    int i4 = blockIdx.x * 256 + threadIdx.x;
    if (i4 < NND * NH / 4) {
        int cg = i4 & 15;
        float4 v  = ((float4*)h)[i4];
        float4 scv = ((const float4*)ss)[cg];
        float4 shv = ((const float4*)(ss + 64))[cg];
        v.x = v.x * scv.x + shv.x;
        v.y = v.y * scv.y + shv.y;
        v.z = v.z * scv.z + shv.z;
        v.w = v.w * scv.w + shv.w;
        ((float4*)h)[i4] = v;
    }
}

extern "C" void kernel_launch(void* const* d_in, const int* in_sizes, int n_in,
                              void* d_out, int out_size, void* d_ws, size_t ws_size,
                              hipStream_t stream) {
    const float* x     = (const float*)d_in[0];
    const int*   ei    = (const int*)d_in[1];
    const float* Wt    = (const float*)d_in[2];
    const float* bt    = (const float*)d_in[3];
    const float* gt    = (const float*)d_in[4];
    const float* bbt   = (const float*)d_in[5];
    const float* W1    = (const float*)d_in[6];
    const float* W2    = (const float*)d_in[7];
    const float* gamma = (const float*)d_in[8];
    const float* beta  = (const float*)d_in[9];
    float* out = (float*)d_out;

    char* ws = (char*)d_ws;
    float*  hA    = (float*)(ws + WS_HA);
    double* stats = (double*)(ws + WS_STATS);
    float*  ss    = (float*)(ws + WS_SS);
    int*    deg   = (int*)(ws + WS_DEG);
    int*    offs  = (int*)(ws + WS_OFFS);
    int*    cur   = (int*)(ws + WS_CUR);
    int*    esrc  = (int*)(ws + WS_ESRC);

    const int* srcv = ei;
    const int* dstv = ei + NED;

    hipMemsetAsync(stats, 0, 4 * 128 * 8, stream);
    hipMemsetAsync(deg, 0, NND * 4, stream);

    const int EB = (NED + 255) / 256;
    k_deg<<<EB, 256, 0, stream>>>(dstv, deg);
    k_scan<<<1, 1024, 0, stream>>>(deg, offs);
    hipMemcpyAsync(cur, offs, NND * 4, hipMemcpyDeviceToDevice, stream);
    k_fill<<<EB, 256, 0, stream>>>(srcv, dstv, cur, esrc);

    const int NT = (NND + 63) / 64;   // 782 tiles

    k_transform<<<NT, 256, 0, stream>>>(x, Wt, bt, hA, stats);
    k_finalize<<<1, 64, 0, stream>>>(stats, gt, bbt, ss);

    // layer 0: hA -> out
    k_layer<<<NT, 256, 0, stream>>>(hA, out, ss, stats + 128, W1, W2, offs, esrc);
    k_finalize<<<1, 64, 0, stream>>>(stats + 128, gamma, beta, ss + 128);
    // layer 1: out -> hA
    k_layer<<<NT, 256, 0, stream>>>(out, hA, ss + 128, stats + 256, W1 + 4096, W2 + 4096, offs, esrc);
    k_finalize<<<1, 64, 0, stream>>>(stats + 256, gamma + 64, beta + 64, ss + 256);
    // layer 2: hA -> out
    k_layer<<<NT, 256, 0, stream>>>(hA, out, ss + 256, stats + 384, W1 + 8192, W2 + 8192, offs, esrc);
    k_finalize<<<1, 64, 0, stream>>>(stats + 384, gamma + 128, beta + 128, ss + 384);

    k_bnout<<<(NND * NH / 4 + 255) / 256, 256, 0, stream>>>(out, ss + 384);
}

// Round 5
// 630.561 us; speedup vs baseline: 1.2425x; 1.2425x over previous
//
#include <hip/hip_runtime.h>

#define NND 50000
#define NED 800000
#define NF  128
#define NH  64

// ---- workspace byte offsets (all 16B aligned) ----
#define WS_HA     0                         // float[NND*64]      12,800,000 B
#define WS_STATS  12800000                  // double[4][128]      4,096 B (sum, sumsq per stage)
#define WS_SS     (WS_STATS + 4*128*8)      // float[4][128]       2,048 B (scale, shift per stage)
#define WS_DEG    (WS_SS + 4*128*4)         // int[NND]
#define WS_OFFS   (WS_DEG + NND*4)          // int[NND+4]
#define WS_CUR    (WS_OFFS + (NND+4)*4)     // int[NND]
#define WS_ESRC   (WS_CUR + NND*4)          // int[NED]

// ---------------- CSR build ----------------
__global__ void k_deg(const int* __restrict__ dst, int* __restrict__ deg) {
    int e = blockIdx.x * 256 + threadIdx.x;
    if (e < NED) atomicAdd(&deg[dst[e]], 1);
}

__global__ __launch_bounds__(1024) void k_scan(const int* __restrict__ deg,
                                               int* __restrict__ offs) {
    __shared__ int sd[1024];
    int t = threadIdx.x;
    const int C = (NND + 1023) / 1024;   // 49
    int s = t * C; if (s > NND) s = NND;
    int e = s + C; if (e > NND) e = NND;
    int loc = 0;
    for (int i = s; i < e; ++i) loc += deg[i];
    sd[t] = loc;
    __syncthreads();
    for (int off = 1; off < 1024; off <<= 1) {
        int v = (t >= off) ? sd[t - off] : 0;
        __syncthreads();
        sd[t] += v;
        __syncthreads();
    }
    int run = sd[t] - loc;   // exclusive prefix
    for (int i = s; i < e; ++i) { offs[i] = run; run += deg[i]; }
    if (t == 1023) offs[NND] = sd[1023];
}

__global__ void k_fill(const int* __restrict__ src, const int* __restrict__ dst,
                       int* __restrict__ cur, int* __restrict__ esrc) {
    int e = blockIdx.x * 256 + threadIdx.x;
    if (e < NED) {
        int d = dst[e];
        int pos = atomicAdd(&cur[d], 1);
        esrc[pos] = src[e];
    }
}

// ---------------- input transform: h0 = x @ W_t + b_t (raw) + stats ----------------
__global__ __launch_bounds__(256) void k_transform(const float* __restrict__ x,
                                                   const float* __restrict__ Wt,
                                                   const float* __restrict__ bt,
                                                   float* __restrict__ outraw,
                                                   double* __restrict__ stats) {
    __shared__ float Wl[NF * NH];   // 32 KB
    __shared__ float sT[64 * 68];   // 17 KB
    int tid = threadIdx.x;

#pragma unroll
    for (int r = 0; r < 8; ++r) {
        int i4 = r * 256 + tid;
        ((float4*)Wl)[i4] = ((const float4*)Wt)[i4];
    }

    int c = tid & 63, w = tid >> 6;
    int tn = tid & 15, tc = tid >> 4;
    int base = blockIdx.x * 64;

    float acc[4][4];
#pragma unroll
    for (int i = 0; i < 4; ++i)
#pragma unroll
        for (int j = 0; j < 4; ++j) acc[i][j] = 0.f;

    for (int half = 0; half < 2; ++half) {
        __syncthreads();
#pragma unroll
        for (int s = 0; s < 16; ++s) {
            int nl = s * 4 + w;
            int n = base + nl;
            float v = 0.f;
            if (n < NND) v = x[(size_t)n * NF + half * 64 + c];
            sT[c * 68 + nl] = v;
        }
        __syncthreads();
#pragma unroll 8
        for (int k = 0; k < 64; ++k) {
            float4 a  = *(const float4*)&sT[k * 68 + tn * 4];
            float4 wv = *(const float4*)&Wl[(half * 64 + k) * NH + tc * 4];
            float av[4]  = {a.x, a.y, a.z, a.w};
            float wvv[4] = {wv.x, wv.y, wv.z, wv.w};
#pragma unroll
            for (int i = 0; i < 4; ++i)
#pragma unroll
                for (int j = 0; j < 4; ++j) acc[i][j] += av[i] * wvv[j];
        }
    }

    float4 bv = ((const float4*)bt)[tc];
    float bj[4] = {bv.x, bv.y, bv.z, bv.w};

    double sum[4] = {0, 0, 0, 0}, ssq[4] = {0, 0, 0, 0};
#pragma unroll
    for (int i = 0; i < 4; ++i) {
        int n = base + tn * 4 + i;
        if (n < NND) {
            float o0 = acc[i][0] + bj[0], o1 = acc[i][1] + bj[1];
            float o2 = acc[i][2] + bj[2], o3 = acc[i][3] + bj[3];
            float4 o = {o0, o1, o2, o3};
            *(float4*)&outraw[(size_t)n * NH + tc * 4] = o;
            sum[0] += o0; ssq[0] += (double)o0 * o0;
            sum[1] += o1; ssq[1] += (double)o1 * o1;
            sum[2] += o2; ssq[2] += (double)o2 * o2;
            sum[3] += o3; ssq[3] += (double)o3 * o3;
        }
    }
#pragma unroll
    for (int m = 1; m < 16; m <<= 1) {
#pragma unroll
        for (int j = 0; j < 4; ++j) {
            sum[j] += __shfl_xor(sum[j], m);
            ssq[j] += __shfl_xor(ssq[j], m);
        }
    }
    if (tn == 0) {
#pragma unroll
        for (int j = 0; j < 4; ++j) {
            atomicAdd(&stats[tc * 4 + j], sum[j]);
            atomicAdd(&stats[64 + tc * 4 + j], ssq[j]);
        }
    }
}

// ---------------- BN finalize ----------------
__global__ void k_finalize(const double* __restrict__ st,
                           const float* __restrict__ g, const float* __restrict__ b,
                           float* __restrict__ ssout) {
    int c = threadIdx.x;
    double mu  = st[c] / (double)NND;
    double var = st[64 + c] / (double)NND - mu * mu;
    if (var < 0.0) var = 0.0;
    double rs = 1.0 / sqrt(var + 1e-5);
    double sc = (double)g[c] * rs;
    ssout[c]      = (float)sc;
    ssout[64 + c] = (float)((double)b[c] - mu * sc);
}

// ---------------- aggregation: wave-per-node gather + BN fold ----------------
// out[n][c] = sc[c]*( raw[n][c] + sum_{j->n} raw[j][c] ) + (deg+1)*sh[c]
__global__ __launch_bounds__(256) void k_agg(const float* __restrict__ inraw,
                                             float* __restrict__ aggout,
                                             const float* __restrict__ ssin,
                                             const int* __restrict__ offs,
                                             const int* __restrict__ esrc) {
    int tid = threadIdx.x;
    int c = tid & 63, w = tid >> 6;
    int n = blockIdx.x * 4 + w;
    if (n >= NND) return;
    float sc = ssin[c], sh = ssin[64 + c];

    float sum = inraw[(size_t)n * NH + c];
    int e0 = offs[n], e1 = offs[n + 1];
    int deg = e1 - e0;
    int e = e0;
    for (; e + 8 <= e1; e += 8) {
        int j0 = esrc[e],     j1 = esrc[e + 1], j2 = esrc[e + 2], j3 = esrc[e + 3];
        int j4 = esrc[e + 4], j5 = esrc[e + 5], j6 = esrc[e + 6], j7 = esrc[e + 7];
        float v0 = inraw[(size_t)j0 * NH + c];
        float v1 = inraw[(size_t)j1 * NH + c];
        float v2 = inraw[(size_t)j2 * NH + c];
        float v3 = inraw[(size_t)j3 * NH + c];
        float v4 = inraw[(size_t)j4 * NH + c];
        float v5 = inraw[(size_t)j5 * NH + c];
        float v6 = inraw[(size_t)j6 * NH + c];
        float v7 = inraw[(size_t)j7 * NH + c];
        sum += ((v0 + v1) + (v2 + v3)) + ((v4 + v5) + (v6 + v7));
    }
    for (; e < e1; ++e) sum += inraw[(size_t)esrc[e] * NH + c];

    aggout[(size_t)n * NH + c] = sc * sum + (float)(deg + 1) * sh;
}

// ---------------- MLP: h = relu(relu(agg @ W1) @ W2), in-place, + stats ----------------
__global__ __launch_bounds__(256) void k_mlp(float* __restrict__ h,
                                             double* __restrict__ statsout,
                                             const float* __restrict__ W1,
                                             const float* __restrict__ W2) {
    __shared__ float W1l[NH * NH];   // 16 KB
    __shared__ float W2l[NH * NH];   // 16 KB
    __shared__ float sT[64 * 68];    // 17 KB
    int tid = threadIdx.x;

#pragma unroll
    for (int r = 0; r < 4; ++r) {
        int i4 = r * 256 + tid;
        ((float4*)W1l)[i4] = ((const float4*)W1)[i4];
        ((float4*)W2l)[i4] = ((const float4*)W2)[i4];
    }

    int base = blockIdx.x * 64;

    // stage agg tile transposed: coalesced float4 global loads
#pragma unroll
    for (int s = 0; s < 4; ++s) {
        int i4 = s * 256 + tid;
        int n = i4 >> 4, q = i4 & 15;
        float4 v = {0.f, 0.f, 0.f, 0.f};
        if (base + n < NND) v = ((const float4*)h)[(size_t)(base + n) * 16 + q];
        sT[(q * 4 + 0) * 68 + n] = v.x;
        sT[(q * 4 + 1) * 68 + n] = v.y;
        sT[(q * 4 + 2) * 68 + n] = v.z;
        sT[(q * 4 + 3) * 68 + n] = v.w;
    }
    __syncthreads();

    int tn = tid & 15, tc = tid >> 4;

    // GEMM1: t1 = relu(agg @ W1)
    float a1[4][4];
#pragma unroll
    for (int i = 0; i < 4; ++i)
#pragma unroll
        for (int j = 0; j < 4; ++j) a1[i][j] = 0.f;
#pragma unroll 8
    for (int k = 0; k < 64; ++k) {
        float4 a  = *(const float4*)&sT[k * 68 + tn * 4];
        float4 wv = *(const float4*)&W1l[k * NH + tc * 4];
        float av[4]  = {a.x, a.y, a.z, a.w};
        float wvv[4] = {wv.x, wv.y, wv.z, wv.w};
#pragma unroll
        for (int i = 0; i < 4; ++i)
#pragma unroll
            for (int j = 0; j < 4; ++j) a1[i][j] += av[i] * wvv[j];
    }
#pragma unroll
    for (int i = 0; i < 4; ++i)
#pragma unroll
        for (int j = 0; j < 4; ++j) a1[i][j] = fmaxf(a1[i][j], 0.f);

    __syncthreads();
#pragma unroll
    for (int j = 0; j < 4; ++j) {
        float4 t = {a1[0][j], a1[1][j], a1[2][j], a1[3][j]};
        *(float4*)&sT[(tc * 4 + j) * 68 + tn * 4] = t;
    }
    __syncthreads();

    // GEMM2: t2 = relu(t1 @ W2)
    float a2[4][4];
#pragma unroll
    for (int i = 0; i < 4; ++i)
#pragma unroll
        for (int j = 0; j < 4; ++j) a2[i][j] = 0.f;
#pragma unroll 8
    for (int k = 0; k < 64; ++k) {
        float4 a  = *(const float4*)&sT[k * 68 + tn * 4];
        float4 wv = *(const float4*)&W2l[k * NH + tc * 4];
        float av[4]  = {a.x, a.y, a.z, a.w};
        float wvv[4] = {wv.x, wv.y, wv.z, wv.w};
#pragma unroll
        for (int i = 0; i < 4; ++i)
#pragma unroll
            for (int j = 0; j < 4; ++j) a2[i][j] += av[i] * wvv[j];
    }

    double sum[4] = {0, 0, 0, 0}, ssq[4] = {0, 0, 0, 0};
#pragma unroll
    for (int i = 0; i < 4; ++i) {
        int n = base + tn * 4 + i;
        if (n < NND) {
            float o0 = fmaxf(a2[i][0], 0.f), o1 = fmaxf(a2[i][1], 0.f);
            float o2 = fmaxf(a2[i][2], 0.f), o3 = fmaxf(a2[i][3], 0.f);
            float4 o = {o0, o1, o2, o3};
            *(float4*)&h[(size_t)n * NH + tc * 4] = o;
            sum[0] += o0; ssq[0] += (double)o0 * o0;
            sum[1] += o1; ssq[1] += (double)o1 * o1;
            sum[2] += o2; ssq[2] += (double)o2 * o2;
            sum[3] += o3; ssq[3] += (double)o3 * o3;
        }
    }
#pragma unroll
    for (int m = 1; m < 16; m <<= 1) {
#pragma unroll
        for (int j = 0; j < 4; ++j) {
            sum[j] += __shfl_xor(sum[j], m);
            ssq[j] += __shfl_xor(ssq[j], m);
        }
    }
    if (tn == 0) {
#pragma unroll
        for (int j = 0; j < 4; ++j) {
            atomicAdd(&statsout[tc * 4 + j], sum[j]);
            atomicAdd(&statsout[64 + tc * 4 + j], ssq[j]);
        }
    }
}

// ---------------- final BN apply, in-place on d_out ----------------
__global__ void k_bnout(float* __restrict__ h, const float* __restrict__ ss) {
    int i4 = blockIdx.x * 256 + threadIdx.x;
    if (i4 < NND * NH / 4) {
        int cg = i4 & 15;
        float4 v  = ((float4*)h)[i4];
        float4 scv = ((const float4*)ss)[cg];
        float4 shv = ((const float4*)(ss + 64))[cg];
        v.x = v.x * scv.x + shv.x;
        v.y = v.y * scv.y + shv.y;
        v.z = v.z * scv.z + shv.z;
        v.w = v.w * scv.w + shv.w;
        ((float4*)h)[i4] = v;
    }
}

extern "C" void kernel_launch(void* const* d_in, const int* in_sizes, int n_in,
                              void* d_out, int out_size, void* d_ws, size_t ws_size,
                              hipStream_t stream) {
    const float* x     = (const float*)d_in[0];
    const int*   ei    = (const int*)d_in[1];
    const float* Wt    = (const float*)d_in[2];
    const float* bt    = (const float*)d_in[3];
    const float* gt    = (const float*)d_in[4];
    const float* bbt   = (const float*)d_in[5];
    const float* W1    = (const float*)d_in[6];
    const float* W2    = (const float*)d_in[7];
    const float* gamma = (const float*)d_in[8];
    const float* beta  = (const float*)d_in[9];
    float* out = (float*)d_out;

    char* ws = (char*)d_ws;
    float*  hA    = (float*)(ws + WS_HA);
    double* stats = (double*)(ws + WS_STATS);
    float*  ss    = (float*)(ws + WS_SS);
    int*    deg   = (int*)(ws + WS_DEG);
    int*    offs  = (int*)(ws + WS_OFFS);
    int*    cur   = (int*)(ws + WS_CUR);
    int*    esrc  = (int*)(ws + WS_ESRC);

    const int* srcv = ei;
    const int* dstv = ei + NED;

    hipMemsetAsync(stats, 0, 4 * 128 * 8, stream);
    hipMemsetAsync(deg, 0, NND * 4, stream);

    const int EB = (NED + 255) / 256;
    k_deg<<<EB, 256, 0, stream>>>(dstv, deg);
    k_scan<<<1, 1024, 0, stream>>>(deg, offs);
    hipMemcpyAsync(cur, offs, NND * 4, hipMemcpyDeviceToDevice, stream);
    k_fill<<<EB, 256, 0, stream>>>(srcv, dstv, cur, esrc);

    const int NT = (NND + 63) / 64;   // 782 tiles
    const int NB = (NND + 3) / 4;     // 12500 agg blocks

    k_transform<<<NT, 256, 0, stream>>>(x, Wt, bt, hA, stats);
    k_finalize<<<1, 64, 0, stream>>>(stats, gt, bbt, ss);

    // layer 0: hA --agg--> out --mlp(in-place)--> out
    k_agg<<<NB, 256, 0, stream>>>(hA, out, ss, offs, esrc);
    k_mlp<<<NT, 256, 0, stream>>>(out, stats + 128, W1, W2);
    k_finalize<<<1, 64, 0, stream>>>(stats + 128, gamma, beta, ss + 128);

    // layer 1: out --agg--> hA --mlp--> hA
    k_agg<<<NB, 256, 0, stream>>>(out, hA, ss + 128, offs, esrc);
    k_mlp<<<NT, 256, 0, stream>>>(hA, stats + 256, W1 + 4096, W2 + 4096);
    k_finalize<<<1, 64, 0, stream>>>(stats + 256, gamma + 64, beta + 64, ss + 256);

    // layer 2: hA --agg--> out --mlp--> out
    k_agg<<<NB, 256, 0, stream>>>(hA, out, ss + 256, offs, esrc);
    k_mlp<<<NT, 256, 0, stream>>>(out, stats + 384, W1 + 8192, W2 + 8192);
    k_finalize<<<1, 64, 0, stream>>>(stats + 384, gamma + 128, beta + 128, ss + 384);

    k_bnout<<<(NND * NH / 4 + 255) / 256, 256, 0, stream>>>(out, ss + 384);
}